// Round 14
// baseline (317.418 us; speedup 1.0000x reference)
//
#include <hip/hip_runtime.h>
#include <cstdint>
#include <cstddef>

typedef unsigned short u16;
typedef __attribute__((ext_vector_type(8))) short bf16x8;
typedef __attribute__((ext_vector_type(4))) float f32x4;

#define DEV __device__ __forceinline__

DEV u16 f2bf(float f) {                 // f32 -> bf16 bits, RNE
  uint32_t b = __float_as_uint(f);
  b += 0x7fffu + ((b >> 16) & 1u);
  return (u16)(b >> 16);
}
DEV float bf2f(u16 u) { return __uint_as_float(((uint32_t)u) << 16); }

DEV void gl16(const u16* g, u16* l) {   // async global->LDS, 16B/lane, dest = wave base + lane*16
  __builtin_amdgcn_global_load_lds(
      (const __attribute__((address_space(1))) void*)g,
      (__attribute__((address_space(3))) void*)l, 16, 0, 0);
}

struct CvtArgs { const float* s[8]; };

// ---------------------------------------------------------------------------
// Merged: LoRA transpose-convert (blocks < 4608) + LN1 token-shift (last 1024)
// ---------------------------------------------------------------------------
__global__ __launch_bounds__(256) void k_cvt_ln(
    const float* __restrict__ w1, const float* __restrict__ w2,
    u16* __restrict__ w1t, u16* __restrict__ w2t,
    const float* __restrict__ x, const float* __restrict__ state,
    const int* __restrict__ ip,
    const float* __restrict__ lw, const float* __restrict__ lb,
    const float* __restrict__ mx,
    u16* __restrict__ xn_o, u16* __restrict__ sx_o, u16* __restrict__ a1_o) {
  __shared__ float ls1[4], ls2[4];
  if (blockIdx.x < 4608) {
    int idx = blockIdx.x * 256 + threadIdx.x;
    if (idx < 655360) {
      int n = idx >> 11, k = idx & 2047;
      w1t[idx] = f2bf(w1[(size_t)k * 320 + n]);
    } else {
      int r = idx - 655360;            // < 524288
      int j = r >> 17, q = r & 131071;
      int n = q >> 6, k2 = q & 63;
      w2t[r] = f2bf(w2[((size_t)(j + 1) * 64 + k2) * 2048 + n]);
    }
  } else {
    int b = blockIdx.x - 4608, t = threadIdx.x;
    const float* xr = x + (size_t)b * 2048;
    float4 v0 = *(const float4*)(xr + t * 8);
    float4 v1 = *(const float4*)(xr + t * 8 + 4);
    float xv[8] = {v0.x, v0.y, v0.z, v0.w, v1.x, v1.y, v1.z, v1.w};
    float s1 = 0.f, s2 = 0.f;
#pragma unroll
    for (int j = 0; j < 8; ++j) { s1 += xv[j]; s2 += xv[j] * xv[j]; }
#pragma unroll
    for (int off = 32; off; off >>= 1) { s1 += __shfl_xor(s1, off); s2 += __shfl_xor(s2, off); }
    int w = t >> 6;
    if ((t & 63) == 0) { ls1[w] = s1; ls2[w] = s2; }
    __syncthreads();
    s1 = ls1[0] + ls1[1] + ls1[2] + ls1[3];
    s2 = ls2[0] + ls2[1] + ls2[2] + ls2[3];
    float mu = s1 * (1.0f / 2048.0f);
    float var = s2 * (1.0f / 2048.0f) - mu * mu;
    float rs = rsqrtf(var + 1e-5f);
    const float* st = state + ((size_t)b * 66 + (size_t)66 * ip[0] + 1) * 2048;
    int e0 = t * 8;
    uint4 xnp, sxp, a1p;
    u16* xnl = (u16*)&xnp; u16* sxl = (u16*)&sxp; u16* a1l = (u16*)&a1p;
#pragma unroll
    for (int j = 0; j < 8; ++j) {
      int e = e0 + j;
      float xn = (xv[j] - mu) * rs * lw[e] + lb[e];
      float sxv = st[e] - xn;
      xnl[j] = f2bf(xn); sxl[j] = f2bf(sxv); a1l[j] = f2bf(xn + sxv * mx[e]);
    }
    size_t o = (size_t)b * 2048 + e0;
    *(uint4*)(xn_o + o) = xnp;
    *(uint4*)(sx_o + o) = sxp;
    *(uint4*)(a1_o + o) = a1p;
  }
}

// xxx = tanh(sum of 4 split-K partials), pack to bf16
__global__ __launch_bounds__(256) void k_tanhpack(const float* __restrict__ p2,
                                                  u16* __restrict__ xb) {
  int idx = blockIdx.x * 256 + threadIdx.x;   // 327680 total
  float s = p2[idx] + p2[327680 + idx] + p2[2 * 327680 + idx] + p2[3 * 327680 + idx];
  xb[idx] = f2bf(tanhf(s));
}

// rr = sigmoid(sum P8[0..1]); kk = relu(sum P8[2..3])^2   (bf16 partials)
__global__ __launch_bounds__(256) void k_act(const u16* __restrict__ p8,
                                             u16* __restrict__ rr, u16* __restrict__ kk) {
  const size_t S = 2097152;
  int gid = blockIdx.x * 256 + threadIdx.x;   // 524288 total, 8 elems each
  size_t e0 = (size_t)(gid & 262143) * 8;
  int isk = gid >= 262144;
  const u16* base = p8 + (isk ? 2 * S : 0) + e0;
  float acc[8] = {};
#pragma unroll
  for (int s = 0; s < 2; ++s) {
    uint4 v = *(const uint4*)(base + (size_t)s * S);
    u16* vl = (u16*)&v;
#pragma unroll
    for (int j = 0; j < 8; ++j) acc[j] += bf2f(vl[j]);
  }
  uint4 p; u16* pl = (u16*)&p;
  if (!isk) {
#pragma unroll
    for (int j = 0; j < 8; ++j) pl[j] = f2bf(1.f / (1.f + __expf(-acc[j])));
    *(uint4*)(rr + e0) = p;
  } else {
#pragma unroll
    for (int j = 0; j < 8; ++j) { float r = acc[j] > 0.f ? acc[j] : 0.f; pl[j] = f2bf(r * r); }
    *(uint4*)(kk + e0) = p;
  }
}

// out = x1(bf16) + rr * (sum P9[0..3])   (bf16 partials)
__global__ __launch_bounds__(256) void k_fin(const u16* __restrict__ x1b,
                                             const u16* __restrict__ p9,
                                             const u16* __restrict__ rr,
                                             float* __restrict__ out) {
  const size_t S = 2097152;
  size_t e0 = ((size_t)blockIdx.x * 256 + threadIdx.x) * 8;
  float acc[8] = {};
#pragma unroll
  for (int s = 0; s < 4; ++s) {
    uint4 v = *(const uint4*)(p9 + (size_t)s * S + e0);
    u16* vl = (u16*)&v;
#pragma unroll
    for (int j = 0; j < 8; ++j) acc[j] += bf2f(vl[j]);
  }
  uint4 xv4 = *(const uint4*)(x1b + e0); u16* xl = (u16*)&xv4;
  uint4 rv = *(const uint4*)(rr + e0); u16* rl = (u16*)&rv;
  float o[8];
#pragma unroll
  for (int j = 0; j < 8; ++j) o[j] = bf2f(xl[j]) + bf2f(rl[j]) * acc[j];
  *(float4*)(out + e0) = make_float4(o[0], o[1], o[2], o[3]);
  *(float4*)(out + e0 + 4) = make_float4(o[4], o[5], o[6], o[7]);
}

// ---------------------------------------------------------------------------
// x1 = x + sum(P6 bf16, 4 planes); LN2 + ffn token-shift; x1 stored bf16
// ---------------------------------------------------------------------------
__global__ __launch_bounds__(256) void k_ln_mix2(
    const float* __restrict__ x, const u16* __restrict__ p6,
    const float* __restrict__ state, const int* __restrict__ ip,
    const float* __restrict__ lw, const float* __restrict__ lb,
    const float* __restrict__ mk, const float* __restrict__ mr,
    u16* __restrict__ xk_o, u16* __restrict__ xr_o, u16* __restrict__ x1b_o) {
  const size_t S = 2097152;
  int b = blockIdx.x, t = threadIdx.x;
  size_t off = (size_t)b * 2048 + t * 8;
  float4 v0 = *(const float4*)(x + off);
  float4 v1 = *(const float4*)(x + off + 4);
  float xv[8] = {v0.x, v0.y, v0.z, v0.w, v1.x, v1.y, v1.z, v1.w};
#pragma unroll
  for (int s = 0; s < 4; ++s) {
    uint4 v = *(const uint4*)(p6 + (size_t)s * S + off);
    u16* vl = (u16*)&v;
#pragma unroll
    for (int j = 0; j < 8; ++j) xv[j] += bf2f(vl[j]);
  }
  uint4 x1p; u16* x1l = (u16*)&x1p;
#pragma unroll
  for (int j = 0; j < 8; ++j) x1l[j] = f2bf(xv[j]);
  *(uint4*)(x1b_o + off) = x1p;
  float s1 = 0.f, s2 = 0.f;
#pragma unroll
  for (int j = 0; j < 8; ++j) { s1 += xv[j]; s2 += xv[j] * xv[j]; }
#pragma unroll
  for (int off2 = 32; off2; off2 >>= 1) { s1 += __shfl_xor(s1, off2); s2 += __shfl_xor(s2, off2); }
  __shared__ float ls1[4], ls2[4];
  int w = t >> 6;
  if ((t & 63) == 0) { ls1[w] = s1; ls2[w] = s2; }
  __syncthreads();
  s1 = ls1[0] + ls1[1] + ls1[2] + ls1[3];
  s2 = ls2[0] + ls2[1] + ls2[2] + ls2[3];
  float mu = s1 * (1.0f / 2048.0f);
  float var = s2 * (1.0f / 2048.0f) - mu * mu;
  float rs = rsqrtf(var + 1e-5f);
  const float* st = state + ((size_t)b * 66 + (size_t)66 * ip[0] + 0) * 2048;
  int e0 = t * 8;
  uint4 xkp, xrp;
  u16* xkl = (u16*)&xkp; u16* xrl = (u16*)&xrp;
#pragma unroll
  for (int j = 0; j < 8; ++j) {
    int e = e0 + j;
    float xn = (xv[j] - mu) * rs * lw[e] + lb[e];
    float sxv = st[e] - xn;
    xkl[j] = f2bf(xn + sxv * mk[e]);
    xrl[j] = f2bf(xn + sxv * mr[e]);
  }
  *(uint4*)(xk_o + off) = xkp;
  *(uint4*)(xr_o + off) = xrp;
}

// ---------------------------------------------------------------------------
enum { EP_STORE = 0, EP_SILU, EP_MIX, EP_STOREF };

struct GemmDesc {
  const u16* A; const u16* B; void* C;
  const void* p1; const void* p2; const float* pvec;
  int lda, ldb, ldc, N, K, k0, ep;
};
struct GemmBatch { GemmDesc g[8]; int bpg; };

// ---------------------------------------------------------------------------
// Small GEMM (m97 structure, 128x128 BK=32) + fused big-8 weight-cvt blocks
// ---------------------------------------------------------------------------
__global__ __launch_bounds__(256, 3) void k_gemmc(GemmBatch bat, int ngemm,
                                                  CvtArgs ca, u16* __restrict__ cdst,
                                                  int cvtoff) {
  if (blockIdx.x >= ngemm) {
    size_t idx = ((size_t)(blockIdx.x - ngemm + cvtoff) * 256 + threadIdx.x) * 8;
    int w = (int)(idx >> 22);
    size_t off = idx & ((1u << 22) - 1);
    const float* s = ca.s[w];
    float4 v0 = *(const float4*)(s + off);
    float4 v1 = *(const float4*)(s + off + 4);
    uint4 p; u16* pl = (u16*)&p;
    pl[0] = f2bf(v0.x); pl[1] = f2bf(v0.y); pl[2] = f2bf(v0.z); pl[3] = f2bf(v0.w);
    pl[4] = f2bf(v1.x); pl[5] = f2bf(v1.y); pl[6] = f2bf(v1.z); pl[7] = f2bf(v1.w);
    *(uint4*)(cdst + ((size_t)w << 22) + off) = p;
    return;
  }
  int gi = blockIdx.x / bat.bpg;
  int bid = blockIdx.x % bat.bpg;
  GemmDesc g = bat.g[gi];
  int ntn = (g.N + 127) >> 7;
  int m0 = (bid / ntn) << 7;
  int n0 = (bid % ntn) << 7;
  __shared__ u16 As[2][128 * 32];
  __shared__ u16 Bs[2][128 * 32];
  int t = threadIdx.x, w = t >> 6, lane = t & 63;
  int wm = w >> 1, wn = w & 1;
  int lr = lane & 15, kb = (lane >> 4) * 8;
  const u16* Ab = g.A + (size_t)(m0 + w * 32 + (lane >> 2)) * g.lda + (lane & 3) * 8;
  const u16* Bb = g.B + (size_t)(n0 + w * 32 + (lane >> 2)) * g.ldb + (lane & 3) * 8;
  int a16 = 16 * g.lda, b16 = 16 * g.ldb;
  int aoff = (w * 32) * 32;
  f32x4 acc[4][4] = {};
  int nt = g.K >> 5;

  auto stage = [&](int buf, int kk) {
    u16* Ad = (u16*)As + buf * 4096 + aoff;
    u16* Bd = (u16*)Bs + buf * 4096 + aoff;
    gl16(Ab + kk, Ad);
    gl16(Ab + kk + a16, Ad + 512);
    gl16(Bb + kk, Bd);
    gl16(Bb + kk + b16, Bd + 512);
  };

  stage(0, g.k0);
  __syncthreads();
  int cur = 0;
  for (int ti = 0; ti < nt; ++ti) {
    if (ti + 1 < nt) stage(cur ^ 1, g.k0 + (ti + 1) * 32);
    const u16* Ac = (const u16*)As + cur * 4096;
    const u16* Bc = (const u16*)Bs + cur * 4096;
    bf16x8 af[4], bfr[4];
#pragma unroll
    for (int m = 0; m < 4; ++m)
      af[m] = *(const bf16x8*)(Ac + (wm * 64 + m * 16 + lr) * 32 + kb);
#pragma unroll
    for (int n = 0; n < 4; ++n)
      bfr[n] = *(const bf16x8*)(Bc + (wn * 64 + n * 16 + lr) * 32 + kb);
#pragma unroll
    for (int m = 0; m < 4; ++m)
#pragma unroll
      for (int n = 0; n < 4; ++n)
        acc[m][n] = __builtin_amdgcn_mfma_f32_16x16x32_bf16(af[m], bfr[n], acc[m][n], 0, 0, 0);
    __syncthreads();
    cur ^= 1;
  }

  int ep = g.ep;
#pragma unroll
  for (int m = 0; m < 4; ++m) {
    int grow0 = m0 + wm * 64 + m * 16 + (lane >> 4) * 4;
#pragma unroll
    for (int n = 0; n < 4; ++n) {
      int gc = n0 + wn * 64 + n * 16 + lr;
      if (gc >= g.N) continue;
#pragma unroll
      for (int q = 0; q < 4; ++q) {
        size_t ci = (size_t)(grow0 + q) * g.ldc + gc;
        float v = acc[m][n][q];
        switch (ep) {
          case EP_STORE: ((u16*)g.C)[ci] = f2bf(v); break;
          case EP_MIX: {
            float xn = bf2f(((const u16*)g.p1)[ci]);
            float sxv = bf2f(((const u16*)g.p2)[ci]);
            ((u16*)g.C)[ci] = f2bf(xn + sxv * (g.pvec[gc] + v));
          } break;
          case EP_STOREF: ((float*)g.C)[ci] = v; break;
          default: break;
        }
      }
    }
  }
}

// ---------------------------------------------------------------------------
// Heavy GEMM A: 128x256 tile, BK=64, 512 thr, ring-3 LDS (144 KB, 1 blk/CU),
// vmcnt(6), T2 swizzle
// ---------------------------------------------------------------------------
__global__ __launch_bounds__(512, 2) void k_gemm2(GemmBatch bat) {
  extern __shared__ u16 lds[];
  int nwg = gridDim.x;
  int wg0 = blockIdx.x;
  int wg = (wg0 & 7) * (nwg >> 3) + (wg0 >> 3);   // XCD swizzle (nwg % 8 == 0)
  int gi = wg / bat.bpg;
  int bid = wg % bat.bpg;
  GemmDesc g = bat.g[gi];
  int ntn = (g.N + 255) >> 8;
  int m0 = (bid / ntn) << 7;
  int n0 = (bid % ntn) << 8;
  int t = threadIdx.x, wv = t >> 6, lane = t & 63;
  int wm = wv >> 2, wn = wv & 3;
  int lr = lane & 15, hi = lane >> 4;

  const u16* asrc[2]; const u16* bsrc[4];
#pragma unroll
  for (int j = 0; j < 2; ++j) {
    int cid = t + 512 * j, r = cid >> 3, c = cid & 7;
    asrc[j] = g.A + (size_t)(m0 + r) * g.lda + ((c ^ (r & 7)) << 3);
  }
#pragma unroll
  for (int j = 0; j < 4; ++j) {
    int cid = t + 512 * j, r = cid >> 3, c = cid & 7;
    bsrc[j] = g.B + (size_t)(n0 + r) * g.ldb + ((c ^ (r & 7)) << 3);
  }
  int au = wv * 512;

  auto stage = [&](int buf, int k) {
    u16* base = lds + buf * 24576;
#pragma unroll
    for (int j = 0; j < 2; ++j) gl16(asrc[j] + k, base + au + j * 4096);
#pragma unroll
    for (int j = 0; j < 4; ++j) gl16(bsrc[j] + k, base + 8192 + au + j * 4096);
  };

  int arow[4], brow[4];
#pragma unroll
  for (int m = 0; m < 4; ++m) arow[m] = wm * 64 + m * 16 + lr;
#pragma unroll
  for (int n = 0; n < 4; ++n) brow[n] = wn * 64 + n * 16 + lr;

  f32x4 acc[4][4] = {};
  int nt = g.K >> 6;
  stage(0, g.k0);
  if (nt > 1) stage(1, g.k0 + 64);

  for (int ti = 0; ti < nt; ++ti) {
    if (ti + 1 < nt) asm volatile("s_waitcnt vmcnt(6)" ::: "memory");
    else             asm volatile("s_waitcnt vmcnt(0)" ::: "memory");
    __builtin_amdgcn_sched_barrier(0);
    __builtin_amdgcn_s_barrier();
    __builtin_amdgcn_sched_barrier(0);
    const u16* buf = lds + (ti % 3) * 24576;
    bf16x8 af[4][2], bf[4][2];
#pragma unroll
    for (int m = 0; m < 4; ++m)
#pragma unroll
      for (int ks = 0; ks < 2; ++ks)
        af[m][ks] = *(const bf16x8*)(buf + arow[m] * 64 + ((((ks << 2) + hi) ^ (arow[m] & 7)) << 3));
#pragma unroll
    for (int n = 0; n < 4; ++n)
#pragma unroll
      for (int ks = 0; ks < 2; ++ks)
        bf[n][ks] = *(const bf16x8*)(buf + 8192 + brow[n] * 64 + ((((ks << 2) + hi) ^ (brow[n] & 7)) << 3));
    if (ti + 2 < nt) stage((ti + 2) % 3, g.k0 + (ti + 2) * 64);
    __builtin_amdgcn_s_setprio(1);
#pragma unroll
    for (int m = 0; m < 4; ++m)
#pragma unroll
      for (int n = 0; n < 4; ++n)
#pragma unroll
        for (int ks = 0; ks < 2; ++ks)
          acc[m][n] = __builtin_amdgcn_mfma_f32_16x16x32_bf16(af[m][ks], bf[n][ks], acc[m][n], 0, 0, 0);
    __builtin_amdgcn_s_setprio(0);
  }

  int ep = g.ep;
#pragma unroll
  for (int m = 0; m < 4; ++m) {
    int grow0 = m0 + wm * 64 + m * 16 + hi * 4;
#pragma unroll
    for (int n = 0; n < 4; ++n) {
      int gc = n0 + wn * 64 + n * 16 + lr;
#pragma unroll
      for (int q = 0; q < 4; ++q) {
        size_t ci = (size_t)(grow0 + q) * g.ldc + gc;
        float v = acc[m][n][q];
        switch (ep) {
          case EP_STORE: ((u16*)g.C)[ci] = f2bf(v); break;
          case EP_SILU:  ((u16*)g.C)[ci] = f2bf(v / (1.f + __expf(-v))); break;
          case EP_STOREF: ((float*)g.C)[ci] = v; break;
          default: break;
        }
      }
    }
  }
}

// ---------------------------------------------------------------------------
// Heavy GEMM B2: 128x256 tile, BK=32, 512 thr, ring-3 LDS (72 KB -> 2 blk/CU),
// counted vmcnt(3), swizzle chunk^=(row>>1)&3 (2-way bank aliasing = free).
// ---------------------------------------------------------------------------
__global__ __launch_bounds__(512, 4) void k_gemm2b(GemmBatch bat) {
  extern __shared__ u16 lds[];
  int nwg = gridDim.x;
  int wg0 = blockIdx.x;
  int wg = (wg0 & 7) * (nwg >> 3) + (wg0 >> 3);   // XCD swizzle (nwg % 8 == 0)
  GemmDesc g = bat.g[wg / bat.bpg];
  int bid = wg % bat.bpg;
  int ntn = (g.N + 255) >> 8;
  int m0 = (bid / ntn) << 7;
  int n0 = (bid % ntn) << 8;
  int t = threadIdx.x, wv = t >> 6, lane = t & 63;
  int wm = wv >> 2, wn = wv & 3;
  int lr = lane & 15, hi = lane >> 4;

  // stage sources: row r = t>>2 (0..127), chunk c = t&3, pre-inverse swizzle
  int r = t >> 2, c = t & 3;
  int cc = ((c ^ ((r >> 1) & 3)) << 3);
  const u16* asrc  = g.A + (size_t)(m0 + r) * g.lda + cc;
  const u16* bsrc0 = g.B + (size_t)(n0 + r) * g.ldb + cc;
  const u16* bsrc1 = g.B + (size_t)(n0 + 128 + r) * g.ldb + cc;
  int au = wv * 512;

  auto stage = [&](int buf, int k) {
    u16* base = lds + buf * 12288;       // 24 KB = 12288 u16 per buffer
    gl16(asrc + k, base + au);           // A: 128x32 = 8 KB
    gl16(bsrc0 + k, base + 4096 + au);   // B rows 0..127
    gl16(bsrc1 + k, base + 8192 + au);   // B rows 128..255
  };

  int arow[4], brow[4];
#pragma unroll
  for (int m = 0; m < 4; ++m) arow[m] = wm * 64 + m * 16 + lr;
#pragma unroll
  for (int n = 0; n < 4; ++n) brow[n] = wn * 64 + n * 16 + lr;
  int swz = ((hi ^ ((lr >> 1) & 3)) << 3);   // row base ≡ 0 mod 16 -> (row>>1)&3 == (lr>>1)&3

  f32x4 acc[4][4] = {};
  int nt = g.K >> 5;
  stage(0, g.k0);
  if (nt > 1) stage(1, g.k0 + 32);

  for (int ti = 0; ti < nt; ++ti) {
    if (ti + 1 < nt) asm volatile("s_waitcnt vmcnt(3)" ::: "memory");
    else             asm volatile("s_waitcnt vmcnt(0)" ::: "memory");
    __builtin_amdgcn_sched_barrier(0);
    __builtin_amdgcn_s_barrier();
    __builtin_amdgcn_sched_barrier(0);
    const u16* buf = lds + (ti % 3) * 12288;
    bf16x8 af[4], bfr[4];
#pragma unroll
    for (int m = 0; m < 4; ++m)
      af[m] = *(const bf16x8*)(buf + arow[m] * 32 + swz);
#pragma unroll
    for (int n = 0; n < 4; ++n)
      bfr[n] = *(const bf16x8*)(buf + 4096 + brow[n] * 32 + swz);
    if (ti + 2 < nt) stage((ti + 2) % 3, g.k0 + (ti + 2) * 32);
    __builtin_amdgcn_s_setprio(1);
#pragma unroll
    for (int m = 0; m < 4; ++m)
#pragma unroll
      for (int n = 0; n < 4; ++n)
        acc[m][n] = __builtin_amdgcn_mfma_f32_16x16x32_bf16(af[m], bfr[n], acc[m][n], 0, 0, 0);
    __builtin_amdgcn_s_setprio(0);
  }

  // bf16 store (partials)
#pragma unroll
  for (int m = 0; m < 4; ++m) {
    int grow0 = m0 + wm * 64 + m * 16 + hi * 4;
#pragma unroll
    for (int n = 0; n < 4; ++n) {
      int gc = n0 + wn * 64 + n * 16 + lr;
#pragma unroll
      for (int q = 0; q < 4; ++q)
        ((u16*)g.C)[(size_t)(grow0 + q) * g.ldc + gc] = f2bf(acc[m][n][q]);
    }
  }
}

// ---------------------------------------------------------------------------
// WKV: sum r/k/v/g split-K bf16 partial pairs, silu(g), readout, groupnorm, gate.
// ---------------------------------------------------------------------------
__global__ __launch_bounds__(256) void k_wkv(
    const u16* __restrict__ p4,
    const float* __restrict__ state, const int* __restrict__ ip,
    const float* __restrict__ fa, const float* __restrict__ gw,
    const float* __restrict__ gbias, u16* __restrict__ t_o) {
  const size_t S = 2097152;
  int t = threadIdx.x, w = t >> 6, lane = t & 63;
  int flat = blockIdx.x * 4 + w;
  int b = flat >> 5, h = flat & 31;
  size_t base = ((size_t)b << 11) + (h << 6) + lane;
  float r  = bf2f(p4[base])         + bf2f(p4[S + base]);
  float kv = bf2f(p4[2 * S + base]) + bf2f(p4[3 * S + base]);
  float vv = bf2f(p4[4 * S + base]) + bf2f(p4[5 * S + base]);
  float gs = bf2f(p4[6 * S + base]) + bf2f(p4[7 * S + base]);
  float gg = gs / (1.f + __expf(-gs));
  float f  = fa[(h << 6) + lane];
  __shared__ float rs[4][64];
  rs[w][lane] = r;
  __syncthreads();
  float c = r * f * kv;
#pragma unroll
  for (int off = 32; off; off >>= 1) c += __shfl_xor(c, off);

  const float* sp = state + ((size_t)b * 66 + (size_t)66 * ip[0] + 2 + 2 * h) * 2048;
  int q = lane >> 4, jj = lane & 15;
  float yp0 = 0.f, yp1 = 0.f, yp2 = 0.f, yp3 = 0.f;
#pragma unroll
  for (int ib = 0; ib < 16; ++ib) {
    int i = ib * 4 + q;
    float4 sv = *(const float4*)(sp + ((i >> 5) * 2048) + ((i & 31) << 6) + jj * 4);
    float ri = rs[w][i];
    yp0 += ri * sv.x; yp1 += ri * sv.y; yp2 += ri * sv.z; yp3 += ri * sv.w;
  }
#pragma unroll
  for (int off = 16; off <= 32; off <<= 1) {
    yp0 += __shfl_xor(yp0, off); yp1 += __shfl_xor(yp1, off);
    yp2 += __shfl_xor(yp2, off); yp3 += __shfl_xor(yp3, off);
  }
  int src = lane >> 2, cc = lane & 3;
  float t0 = __shfl(yp0, src), t1 = __shfl(yp1, src);
  float t2 = __shfl(yp2, src), t3 = __shfl(yp3, src);
  float y = cc == 0 ? t0 : cc == 1 ? t1 : cc == 2 ? t2 : t3;
  y += c * vv;
  float s1 = y, s2 = y * y;
#pragma unroll
  for (int off = 32; off; off >>= 1) { s1 += __shfl_xor(s1, off); s2 += __shfl_xor(s2, off); }
  float mu = s1 * (1.f / 64.f);
  float var = s2 * (1.f / 64.f) - mu * mu;
  float yn = (y - mu) * rsqrtf(var + 1e-5f);
  float tg = (yn * gw[(h << 6) + lane] + gbias[(h << 6) + lane]) * gg;
  t_o[base] = f2bf(tg);
}

// ---------------------------------------------------------------------------
extern "C" void kernel_launch(void* const* d_in, const int* in_sizes, int n_in,
                              void* d_out, int out_size, void* d_ws, size_t ws_size,
                              hipStream_t stream) {
  const float* x      = (const float*)d_in[0];
  const float* state  = (const float*)d_in[1];
  const float* ln1_w  = (const float*)d_in[2];
  const float* ln1_b  = (const float*)d_in[3];
  const float* ln2_w  = (const float*)d_in[4];
  const float* ln2_b  = (const float*)d_in[5];
  const float* maa_x  = (const float*)d_in[6];
  const float* maa_k  = (const float*)d_in[8];
  const float* maa_v  = (const float*)d_in[9];
  const float* maa_r  = (const float*)d_in[10];
  const float* maa_g  = (const float*)d_in[11];
  const float* maa_w1 = (const float*)d_in[12];
  const float* maa_w2 = (const float*)d_in[13];
  // decay (14,15,16) dead: w gate never reaches the returned output
  const float* faaaa  = (const float*)d_in[17];
  const float* Wr     = (const float*)d_in[18];
  const float* Wk     = (const float*)d_in[19];
  const float* Wv     = (const float*)d_in[20];
  const float* Wo     = (const float*)d_in[21];
  const float* Wg     = (const float*)d_in[22];
  const float* gn_w   = (const float*)d_in[23];
  const float* gn_b   = (const float*)d_in[24];
  const float* fmk    = (const float*)d_in[25];
  const float* fmr    = (const float*)d_in[26];
  const float* fWk    = (const float*)d_in[27];
  const float* fWr    = (const float*)d_in[28];
  const float* fWv    = (const float*)d_in[29];
  const int*   ip     = (const int*)d_in[30];
  float* out = (float*)d_out;

  char* wsb = (char*)d_ws;
  const size_t MB = 1ull << 20;
  u16* wbf   = (u16*)(wsb + 0 * MB);     // 8 x [2048,2048] bf16 = 64 MB
  u16* w1t   = (u16*)(wsb + 64 * MB);
  u16* w2t   = (u16*)(wsb + 66 * MB);
  u16* xn    = (u16*)(wsb + 68 * MB);
  u16* sx    = (u16*)(wsb + 72 * MB);
  u16* a1    = (u16*)(wsb + 76 * MB);
  float* p2  = (float*)(wsb + 80 * MB);  // [4][1024,320] f32
  u16* xxx   = (u16*)(wsb + 86 * MB);
  u16* xk    = (u16*)(wsb + 87 * MB);
  u16* xv    = (u16*)(wsb + 91 * MB);
  u16* xr    = (u16*)(wsb + 95 * MB);
  u16* xg    = (u16*)(wsb + 99 * MB);
  u16* p4    = (u16*)(wsb + 103 * MB);   // [8][1024,2048] bf16 (r0,r1,k0,k1,v0,v1,g0,g1)
  u16* tb    = (u16*)(wsb + 135 * MB);
  u16* p6    = (u16*)(wsb + 139 * MB);   // [4][1024,2048] bf16
  u16* x1b   = (u16*)(wsb + 155 * MB);   // [1024,2048] bf16
  u16* xk2   = (u16*)(wsb + 159 * MB);
  u16* xr2   = (u16*)(wsb + 163 * MB);
  u16* p8    = (u16*)(wsb + 167 * MB);   // [4][1024,2048] bf16
  u16* rr    = (u16*)(wsb + 183 * MB);
  u16* kkb   = (u16*)(wsb + 187 * MB);
  u16* p9    = (u16*)(wsb + 191 * MB);   // [4][1024,2048] bf16; end 207 MB

  const size_t WSQ = 4194304, S = 2097152;
  u16* bWr = wbf + 0 * WSQ; u16* bWk = wbf + 1 * WSQ; u16* bWv = wbf + 2 * WSQ;
  u16* bWg = wbf + 3 * WSQ; u16* bWo = wbf + 4 * WSQ; u16* bfWr = wbf + 5 * WSQ;
  u16* bfWk = wbf + 6 * WSQ; u16* bfWv = wbf + 7 * WSQ;

  auto mkd = [](const u16* A, const u16* B, void* C, const void* p1,
                const void* p2_, const float* pvec, int lda, int ldb, int ldc,
                int N, int K, int k0, int epf) {
    GemmDesc d; d.A = A; d.B = B; d.C = C; d.p1 = p1; d.p2 = p2_; d.pvec = pvec;
    d.lda = lda; d.ldb = ldb; d.ldc = ldc; d.N = N; d.K = K; d.k0 = k0; d.ep = epf;
    return d;
  };

  CvtArgs ca; ca.s[0] = Wr; ca.s[1] = Wk; ca.s[2] = Wv; ca.s[3] = Wg;
  ca.s[4] = Wo; ca.s[5] = fWr; ca.s[6] = fWk; ca.s[7] = fWv;

  static const int LDS2  = 147456;       // k_gemm2:  3 x 48 KB ring
  static const int LDS2B = 73728;        // k_gemm2b: 3 x 24 KB ring (2 blocks/CU)
  hipFuncSetAttribute((const void*)k_gemm2,
                      hipFuncAttributeMaxDynamicSharedMemorySize, LDS2);
  hipFuncSetAttribute((const void*)k_gemm2b,
                      hipFuncAttributeMaxDynamicSharedMemorySize, LDS2B);

  // 1) LoRA weight transpose-cvt + LN1 token-shift
  k_cvt_ln<<<5632, 256, 0, stream>>>(maa_w1, maa_w2, w1t, w2t,
                                     x, state, ip, ln1_w, ln1_b, maa_x, xn, sx, a1);

  // 2) p2[j] = a1 @ w1t^T (K-slice j)  + big-8 cvt first half (Wr,Wk,Wv,Wg)
  {
    GemmBatch g{}; g.bpg = 8 * 3;
    for (int j = 0; j < 4; ++j)
      g.g[j] = mkd(a1, w1t, p2 + (size_t)j * 327680, nullptr, nullptr, nullptr,
                   2048, 2048, 320, 320, 512, j * 512, EP_STOREF);
    k_gemmc<<<96 + 8192, 256, 0, stream>>>(g, 96, ca, wbf, 0);
  }
  k_tanhpack<<<1280, 256, 0, stream>>>(p2, xxx);

  // 3) LoRA mix j=1..4  + big-8 cvt second half (Wo,fWr,fWk,fWv)
  {
    GemmBatch g{}; g.bpg = 8 * 16;
    const float* mv[4] = {maa_k, maa_v, maa_r, maa_g};
    u16* tv[4] = {xk, xv, xr, xg};
    for (int j = 1; j <= 4; ++j)
      g.g[j - 1] = mkd(xxx + j * 64, w2t + (size_t)(j - 1) * 131072, tv[j - 1],
                       xn, sx, mv[j - 1], 320, 64, 2048, 2048, 64, 0, EP_MIX);
    k_gemmc<<<512 + 8192, 256, 0, stream>>>(g, 512, ca, wbf, 8192);
  }

  // 4) r,k,v,g GEMMs -> bf16 partial pairs (k_gemm2b, split-K 2, 512 blocks, 2/CU)
  {
    GemmBatch g{}; g.bpg = 64;
    const u16* av[4] = {xr, xk, xv, xg};
    const u16* bv[4] = {bWr, bWk, bWv, bWg};
    for (int q = 0; q < 4; ++q)
      for (int s = 0; s < 2; ++s)
        g.g[q * 2 + s] = mkd(av[q], bv[q], p4 + (size_t)(q * 2 + s) * S,
                             nullptr, nullptr, nullptr, 2048, 2048, 2048,
                             2048, 1024, s * 1024, EP_STORE);
    k_gemm2b<<<512, 512, LDS2B, stream>>>(g);
  }

  // 5) WKV + groupnorm + silu-gate (sums p4 pairs)
  k_wkv<<<8192, 256, 0, stream>>>(p4, state, ip, faaaa, gn_w, gn_b, tb);

  // 6) p6[s] = tb @ Wo^T (k_gemm2, split-K 4, 256 blocks, bf16 partials)
  {
    GemmBatch g{}; g.bpg = 8 * 8;
    for (int s = 0; s < 4; ++s)
      g.g[s] = mkd(tb, bWo, p6 + (size_t)s * S, nullptr, nullptr, nullptr,
                   2048, 2048, 2048, 2048, 512, s * 512, EP_STORE);
    k_gemm2<<<256, 512, LDS2, stream>>>(g);
  }

  // 7) x1 = x + sum(p6); LN2 + ffn shift (x1 stored bf16)
  k_ln_mix2<<<1024, 256, 0, stream>>>(x, p6, state, ip, ln2_w, ln2_b, fmk, fmr,
                                      xk2, xr2, x1b);

  // 8) p8[0..1] = xr2@fWr^T; p8[2..3] = xk2@fWk^T (k_gemm2, split-K 2, 256 blocks)
  {
    GemmBatch g{}; g.bpg = 8 * 8;
    for (int s = 0; s < 2; ++s) {
      g.g[s]     = mkd(xr2, bfWr, p8 + (size_t)s * S, nullptr, nullptr, nullptr,
                       2048, 2048, 2048, 2048, 1024, s * 1024, EP_STORE);
      g.g[2 + s] = mkd(xk2, bfWk, p8 + (size_t)(2 + s) * S, nullptr, nullptr, nullptr,
                       2048, 2048, 2048, 2048, 1024, s * 1024, EP_STORE);
    }
    k_gemm2<<<256, 512, LDS2, stream>>>(g);
  }
  k_act<<<2048, 256, 0, stream>>>(p8, rr, kkb);

  // 9) p9[s] = kk @ fWv^T (k_gemm2, split-K 4, 256 blocks, bf16 partials)
  {
    GemmBatch g{}; g.bpg = 8 * 8;
    for (int s = 0; s < 4; ++s)
      g.g[s] = mkd(kkb, bfWv, p9 + (size_t)s * S, nullptr, nullptr, nullptr,
                   2048, 2048, 2048, 2048, 512, s * 512, EP_STORE);
    k_gemm2<<<256, 512, LDS2, stream>>>(g);
  }

  // 10) out = x1b + rr * sum(p9)
  k_fin<<<1024, 256, 0, stream>>>(x1b, p9, rr, out);
}

// Round 15
// 310.823 us; speedup vs baseline: 1.0212x; 1.0212x over previous
//
#include <hip/hip_runtime.h>
#include <cstdint>
#include <cstddef>

typedef unsigned short u16;
typedef __attribute__((ext_vector_type(8))) short bf16x8;
typedef __attribute__((ext_vector_type(4))) float f32x4;

#define DEV __device__ __forceinline__

DEV u16 f2bf(float f) {                 // f32 -> bf16 bits, RNE
  uint32_t b = __float_as_uint(f);
  b += 0x7fffu + ((b >> 16) & 1u);
  return (u16)(b >> 16);
}
DEV float bf2f(u16 u) { return __uint_as_float(((uint32_t)u) << 16); }

DEV void gl16(const u16* g, u16* l) {   // async global->LDS, 16B/lane, dest = wave base + lane*16
  __builtin_amdgcn_global_load_lds(
      (const __attribute__((address_space(1))) void*)g,
      (__attribute__((address_space(3))) void*)l, 16, 0, 0);
}

struct CvtArgs { const float* s[8]; };

// ---------------------------------------------------------------------------
// Merged: LoRA transpose-convert (blocks < 4608) + LN1 token-shift (last 1024)
// ---------------------------------------------------------------------------
__global__ __launch_bounds__(256) void k_cvt_ln(
    const float* __restrict__ w1, const float* __restrict__ w2,
    u16* __restrict__ w1t, u16* __restrict__ w2t,
    const float* __restrict__ x, const float* __restrict__ state,
    const int* __restrict__ ip,
    const float* __restrict__ lw, const float* __restrict__ lb,
    const float* __restrict__ mx,
    u16* __restrict__ xn_o, u16* __restrict__ sx_o, u16* __restrict__ a1_o) {
  __shared__ float ls1[4], ls2[4];
  if (blockIdx.x < 4608) {
    int idx = blockIdx.x * 256 + threadIdx.x;
    if (idx < 655360) {
      int n = idx >> 11, k = idx & 2047;
      w1t[idx] = f2bf(w1[(size_t)k * 320 + n]);
    } else {
      int r = idx - 655360;            // < 524288
      int j = r >> 17, q = r & 131071;
      int n = q >> 6, k2 = q & 63;
      w2t[r] = f2bf(w2[((size_t)(j + 1) * 64 + k2) * 2048 + n]);
    }
  } else {
    int b = blockIdx.x - 4608, t = threadIdx.x;
    const float* xr = x + (size_t)b * 2048;
    float4 v0 = *(const float4*)(xr + t * 8);
    float4 v1 = *(const float4*)(xr + t * 8 + 4);
    float xv[8] = {v0.x, v0.y, v0.z, v0.w, v1.x, v1.y, v1.z, v1.w};
    float s1 = 0.f, s2 = 0.f;
#pragma unroll
    for (int j = 0; j < 8; ++j) { s1 += xv[j]; s2 += xv[j] * xv[j]; }
#pragma unroll
    for (int off = 32; off; off >>= 1) { s1 += __shfl_xor(s1, off); s2 += __shfl_xor(s2, off); }
    int w = t >> 6;
    if ((t & 63) == 0) { ls1[w] = s1; ls2[w] = s2; }
    __syncthreads();
    s1 = ls1[0] + ls1[1] + ls1[2] + ls1[3];
    s2 = ls2[0] + ls2[1] + ls2[2] + ls2[3];
    float mu = s1 * (1.0f / 2048.0f);
    float var = s2 * (1.0f / 2048.0f) - mu * mu;
    float rs = rsqrtf(var + 1e-5f);
    const float* st = state + ((size_t)b * 66 + (size_t)66 * ip[0] + 1) * 2048;
    int e0 = t * 8;
    uint4 xnp, sxp, a1p;
    u16* xnl = (u16*)&xnp; u16* sxl = (u16*)&sxp; u16* a1l = (u16*)&a1p;
#pragma unroll
    for (int j = 0; j < 8; ++j) {
      int e = e0 + j;
      float xn = (xv[j] - mu) * rs * lw[e] + lb[e];
      float sxv = st[e] - xn;
      xnl[j] = f2bf(xn); sxl[j] = f2bf(sxv); a1l[j] = f2bf(xn + sxv * mx[e]);
    }
    size_t o = (size_t)b * 2048 + e0;
    *(uint4*)(xn_o + o) = xnp;
    *(uint4*)(sx_o + o) = sxp;
    *(uint4*)(a1_o + o) = a1p;
  }
}

// xxx = tanh(sum of 4 split-K partials), pack to bf16
__global__ __launch_bounds__(256) void k_tanhpack(const float* __restrict__ p2,
                                                  u16* __restrict__ xb) {
  int idx = blockIdx.x * 256 + threadIdx.x;   // 327680 total
  float s = p2[idx] + p2[327680 + idx] + p2[2 * 327680 + idx] + p2[3 * 327680 + idx];
  xb[idx] = f2bf(tanhf(s));
}

// rr = sigmoid(sum P8[0..1]); kk = relu(sum P8[2..3])^2   (bf16 partials)
__global__ __launch_bounds__(256) void k_act(const u16* __restrict__ p8,
                                             u16* __restrict__ rr, u16* __restrict__ kk) {
  const size_t S = 2097152;
  int gid = blockIdx.x * 256 + threadIdx.x;   // 524288 total, 8 elems each
  size_t e0 = (size_t)(gid & 262143) * 8;
  int isk = gid >= 262144;
  const u16* base = p8 + (isk ? 2 * S : 0) + e0;
  float acc[8] = {};
#pragma unroll
  for (int s = 0; s < 2; ++s) {
    uint4 v = *(const uint4*)(base + (size_t)s * S);
    u16* vl = (u16*)&v;
#pragma unroll
    for (int j = 0; j < 8; ++j) acc[j] += bf2f(vl[j]);
  }
  uint4 p; u16* pl = (u16*)&p;
  if (!isk) {
#pragma unroll
    for (int j = 0; j < 8; ++j) pl[j] = f2bf(1.f / (1.f + __expf(-acc[j])));
    *(uint4*)(rr + e0) = p;
  } else {
#pragma unroll
    for (int j = 0; j < 8; ++j) { float r = acc[j] > 0.f ? acc[j] : 0.f; pl[j] = f2bf(r * r); }
    *(uint4*)(kk + e0) = p;
  }
}

// out = x1(bf16) + rr * (sum P9[0..3])   (bf16 partials)
__global__ __launch_bounds__(256) void k_fin(const u16* __restrict__ x1b,
                                             const u16* __restrict__ p9,
                                             const u16* __restrict__ rr,
                                             float* __restrict__ out) {
  const size_t S = 2097152;
  size_t e0 = ((size_t)blockIdx.x * 256 + threadIdx.x) * 8;
  float acc[8] = {};
#pragma unroll
  for (int s = 0; s < 4; ++s) {
    uint4 v = *(const uint4*)(p9 + (size_t)s * S + e0);
    u16* vl = (u16*)&v;
#pragma unroll
    for (int j = 0; j < 8; ++j) acc[j] += bf2f(vl[j]);
  }
  uint4 xv4 = *(const uint4*)(x1b + e0); u16* xl = (u16*)&xv4;
  uint4 rv = *(const uint4*)(rr + e0); u16* rl = (u16*)&rv;
  float o[8];
#pragma unroll
  for (int j = 0; j < 8; ++j) o[j] = bf2f(xl[j]) + bf2f(rl[j]) * acc[j];
  *(float4*)(out + e0) = make_float4(o[0], o[1], o[2], o[3]);
  *(float4*)(out + e0 + 4) = make_float4(o[4], o[5], o[6], o[7]);
}

// ---------------------------------------------------------------------------
// x1 = x + sum(P6 bf16, 4 planes); LN2 + ffn token-shift; x1 stored bf16
// ---------------------------------------------------------------------------
__global__ __launch_bounds__(256) void k_ln_mix2(
    const float* __restrict__ x, const u16* __restrict__ p6,
    const float* __restrict__ state, const int* __restrict__ ip,
    const float* __restrict__ lw, const float* __restrict__ lb,
    const float* __restrict__ mk, const float* __restrict__ mr,
    u16* __restrict__ xk_o, u16* __restrict__ xr_o, u16* __restrict__ x1b_o) {
  const size_t S = 2097152;
  int b = blockIdx.x, t = threadIdx.x;
  size_t off = (size_t)b * 2048 + t * 8;
  float4 v0 = *(const float4*)(x + off);
  float4 v1 = *(const float4*)(x + off + 4);
  float xv[8] = {v0.x, v0.y, v0.z, v0.w, v1.x, v1.y, v1.z, v1.w};
#pragma unroll
  for (int s = 0; s < 4; ++s) {
    uint4 v = *(const uint4*)(p6 + (size_t)s * S + off);
    u16* vl = (u16*)&v;
#pragma unroll
    for (int j = 0; j < 8; ++j) xv[j] += bf2f(vl[j]);
  }
  uint4 x1p; u16* x1l = (u16*)&x1p;
#pragma unroll
  for (int j = 0; j < 8; ++j) x1l[j] = f2bf(xv[j]);
  *(uint4*)(x1b_o + off) = x1p;
  float s1 = 0.f, s2 = 0.f;
#pragma unroll
  for (int j = 0; j < 8; ++j) { s1 += xv[j]; s2 += xv[j] * xv[j]; }
#pragma unroll
  for (int off2 = 32; off2; off2 >>= 1) { s1 += __shfl_xor(s1, off2); s2 += __shfl_xor(s2, off2); }
  __shared__ float ls1[4], ls2[4];
  int w = t >> 6;
  if ((t & 63) == 0) { ls1[w] = s1; ls2[w] = s2; }
  __syncthreads();
  s1 = ls1[0] + ls1[1] + ls1[2] + ls1[3];
  s2 = ls2[0] + ls2[1] + ls2[2] + ls2[3];
  float mu = s1 * (1.0f / 2048.0f);
  float var = s2 * (1.0f / 2048.0f) - mu * mu;
  float rs = rsqrtf(var + 1e-5f);
  const float* st = state + ((size_t)b * 66 + (size_t)66 * ip[0] + 0) * 2048;
  int e0 = t * 8;
  uint4 xkp, xrp;
  u16* xkl = (u16*)&xkp; u16* xrl = (u16*)&xrp;
#pragma unroll
  for (int j = 0; j < 8; ++j) {
    int e = e0 + j;
    float xn = (xv[j] - mu) * rs * lw[e] + lb[e];
    float sxv = st[e] - xn;
    xkl[j] = f2bf(xn + sxv * mk[e]);
    xrl[j] = f2bf(xn + sxv * mr[e]);
  }
  *(uint4*)(xk_o + off) = xkp;
  *(uint4*)(xr_o + off) = xrp;
}

// ---------------------------------------------------------------------------
enum { EP_STORE = 0, EP_SILU, EP_MIX, EP_STOREF };

struct GemmDesc {
  const u16* A; const u16* B; void* C;
  const void* p1; const void* p2; const float* pvec;
  int lda, ldb, ldc, N, K, k0, ep;
};
struct GemmBatch { GemmDesc g[8]; int bpg; };

// ---------------------------------------------------------------------------
// Small GEMM (m97 structure, 128x128 BK=32) + fused big-8 weight-cvt blocks
// ---------------------------------------------------------------------------
__global__ __launch_bounds__(256, 3) void k_gemmc(GemmBatch bat, int ngemm,
                                                  CvtArgs ca, u16* __restrict__ cdst,
                                                  int cvtoff) {
  if (blockIdx.x >= ngemm) {
    size_t idx = ((size_t)(blockIdx.x - ngemm + cvtoff) * 256 + threadIdx.x) * 8;
    int w = (int)(idx >> 22);
    size_t off = idx & ((1u << 22) - 1);
    const float* s = ca.s[w];
    float4 v0 = *(const float4*)(s + off);
    float4 v1 = *(const float4*)(s + off + 4);
    uint4 p; u16* pl = (u16*)&p;
    pl[0] = f2bf(v0.x); pl[1] = f2bf(v0.y); pl[2] = f2bf(v0.z); pl[3] = f2bf(v0.w);
    pl[4] = f2bf(v1.x); pl[5] = f2bf(v1.y); pl[6] = f2bf(v1.z); pl[7] = f2bf(v1.w);
    *(uint4*)(cdst + ((size_t)w << 22) + off) = p;
    return;
  }
  int gi = blockIdx.x / bat.bpg;
  int bid = blockIdx.x % bat.bpg;
  GemmDesc g = bat.g[gi];
  int ntn = (g.N + 127) >> 7;
  int m0 = (bid / ntn) << 7;
  int n0 = (bid % ntn) << 7;
  __shared__ u16 As[2][128 * 32];
  __shared__ u16 Bs[2][128 * 32];
  int t = threadIdx.x, w = t >> 6, lane = t & 63;
  int wm = w >> 1, wn = w & 1;
  int lr = lane & 15, kb = (lane >> 4) * 8;
  const u16* Ab = g.A + (size_t)(m0 + w * 32 + (lane >> 2)) * g.lda + (lane & 3) * 8;
  const u16* Bb = g.B + (size_t)(n0 + w * 32 + (lane >> 2)) * g.ldb + (lane & 3) * 8;
  int a16 = 16 * g.lda, b16 = 16 * g.ldb;
  int aoff = (w * 32) * 32;
  f32x4 acc[4][4] = {};
  int nt = g.K >> 5;

  auto stage = [&](int buf, int kk) {
    u16* Ad = (u16*)As + buf * 4096 + aoff;
    u16* Bd = (u16*)Bs + buf * 4096 + aoff;
    gl16(Ab + kk, Ad);
    gl16(Ab + kk + a16, Ad + 512);
    gl16(Bb + kk, Bd);
    gl16(Bb + kk + b16, Bd + 512);
  };

  stage(0, g.k0);
  __syncthreads();
  int cur = 0;
  for (int ti = 0; ti < nt; ++ti) {
    if (ti + 1 < nt) stage(cur ^ 1, g.k0 + (ti + 1) * 32);
    const u16* Ac = (const u16*)As + cur * 4096;
    const u16* Bc = (const u16*)Bs + cur * 4096;
    bf16x8 af[4], bfr[4];
#pragma unroll
    for (int m = 0; m < 4; ++m)
      af[m] = *(const bf16x8*)(Ac + (wm * 64 + m * 16 + lr) * 32 + kb);
#pragma unroll
    for (int n = 0; n < 4; ++n)
      bfr[n] = *(const bf16x8*)(Bc + (wn * 64 + n * 16 + lr) * 32 + kb);
#pragma unroll
    for (int m = 0; m < 4; ++m)
#pragma unroll
      for (int n = 0; n < 4; ++n)
        acc[m][n] = __builtin_amdgcn_mfma_f32_16x16x32_bf16(af[m], bfr[n], acc[m][n], 0, 0, 0);
    __syncthreads();
    cur ^= 1;
  }

  int ep = g.ep;
#pragma unroll
  for (int m = 0; m < 4; ++m) {
    int grow0 = m0 + wm * 64 + m * 16 + (lane >> 4) * 4;
#pragma unroll
    for (int n = 0; n < 4; ++n) {
      int gc = n0 + wn * 64 + n * 16 + lr;
      if (gc >= g.N) continue;
#pragma unroll
      for (int q = 0; q < 4; ++q) {
        size_t ci = (size_t)(grow0 + q) * g.ldc + gc;
        float v = acc[m][n][q];
        switch (ep) {
          case EP_STORE: ((u16*)g.C)[ci] = f2bf(v); break;
          case EP_MIX: {
            float xn = bf2f(((const u16*)g.p1)[ci]);
            float sxv = bf2f(((const u16*)g.p2)[ci]);
            ((u16*)g.C)[ci] = f2bf(xn + sxv * (g.pvec[gc] + v));
          } break;
          case EP_STOREF: ((float*)g.C)[ci] = v; break;
          default: break;
        }
      }
    }
  }
}

// ---------------------------------------------------------------------------
// Heavy GEMM A: 128x256 tile, BK=64, 512 thr, ring-3 LDS, vmcnt(6), T2 swizzle
// ---------------------------------------------------------------------------
__global__ __launch_bounds__(512, 2) void k_gemm2(GemmBatch bat) {
  extern __shared__ u16 lds[];
  int nwg = gridDim.x;
  int wg0 = blockIdx.x;
  int wg = (wg0 & 7) * (nwg >> 3) + (wg0 >> 3);   // XCD swizzle (nwg % 8 == 0)
  int gi = wg / bat.bpg;
  int bid = wg % bat.bpg;
  GemmDesc g = bat.g[gi];
  int ntn = (g.N + 255) >> 8;
  int m0 = (bid / ntn) << 7;
  int n0 = (bid % ntn) << 8;
  int t = threadIdx.x, wv = t >> 6, lane = t & 63;
  int wm = wv >> 2, wn = wv & 3;
  int lr = lane & 15, hi = lane >> 4;

  const u16* asrc[2]; const u16* bsrc[4];
#pragma unroll
  for (int j = 0; j < 2; ++j) {
    int cid = t + 512 * j, r = cid >> 3, c = cid & 7;
    asrc[j] = g.A + (size_t)(m0 + r) * g.lda + ((c ^ (r & 7)) << 3);
  }
#pragma unroll
  for (int j = 0; j < 4; ++j) {
    int cid = t + 512 * j, r = cid >> 3, c = cid & 7;
    bsrc[j] = g.B + (size_t)(n0 + r) * g.ldb + ((c ^ (r & 7)) << 3);
  }
  int au = wv * 512;

  auto stage = [&](int buf, int k) {
    u16* base = lds + buf * 24576;
#pragma unroll
    for (int j = 0; j < 2; ++j) gl16(asrc[j] + k, base + au + j * 4096);
#pragma unroll
    for (int j = 0; j < 4; ++j) gl16(bsrc[j] + k, base + 8192 + au + j * 4096);
  };

  int arow[4], brow[4];
#pragma unroll
  for (int m = 0; m < 4; ++m) arow[m] = wm * 64 + m * 16 + lr;
#pragma unroll
  for (int n = 0; n < 4; ++n) brow[n] = wn * 64 + n * 16 + lr;

  f32x4 acc[4][4] = {};
  int nt = g.K >> 6;
  stage(0, g.k0);
  if (nt > 1) stage(1, g.k0 + 64);

  for (int ti = 0; ti < nt; ++ti) {
    if (ti + 1 < nt) asm volatile("s_waitcnt vmcnt(6)" ::: "memory");
    else             asm volatile("s_waitcnt vmcnt(0)" ::: "memory");
    __builtin_amdgcn_sched_barrier(0);
    __builtin_amdgcn_s_barrier();
    __builtin_amdgcn_sched_barrier(0);
    const u16* buf = lds + (ti % 3) * 24576;
    bf16x8 af[4][2], bf[4][2];
#pragma unroll
    for (int m = 0; m < 4; ++m)
#pragma unroll
      for (int ks = 0; ks < 2; ++ks)
        af[m][ks] = *(const bf16x8*)(buf + arow[m] * 64 + ((((ks << 2) + hi) ^ (arow[m] & 7)) << 3));
#pragma unroll
    for (int n = 0; n < 4; ++n)
#pragma unroll
      for (int ks = 0; ks < 2; ++ks)
        bf[n][ks] = *(const bf16x8*)(buf + 8192 + brow[n] * 64 + ((((ks << 2) + hi) ^ (brow[n] & 7)) << 3));
    if (ti + 2 < nt) stage((ti + 2) % 3, g.k0 + (ti + 2) * 64);
    __builtin_amdgcn_s_setprio(1);
#pragma unroll
    for (int m = 0; m < 4; ++m)
#pragma unroll
      for (int n = 0; n < 4; ++n)
#pragma unroll
        for (int ks = 0; ks < 2; ++ks)
          acc[m][n] = __builtin_amdgcn_mfma_f32_16x16x32_bf16(af[m][ks], bf[n][ks], acc[m][n], 0, 0, 0);
    __builtin_amdgcn_s_setprio(0);
  }

  int ep = g.ep;
#pragma unroll
  for (int m = 0; m < 4; ++m) {
    int grow0 = m0 + wm * 64 + m * 16 + hi * 4;
#pragma unroll
    for (int n = 0; n < 4; ++n) {
      int gc = n0 + wn * 64 + n * 16 + lr;
#pragma unroll
      for (int q = 0; q < 4; ++q) {
        size_t ci = (size_t)(grow0 + q) * g.ldc + gc;
        float v = acc[m][n][q];
        switch (ep) {
          case EP_STORE: ((u16*)g.C)[ci] = f2bf(v); break;
          case EP_SILU:  ((u16*)g.C)[ci] = f2bf(v / (1.f + __expf(-v))); break;
          case EP_STOREF: ((float*)g.C)[ci] = v; break;
          default: break;
        }
      }
    }
  }
}

// ---------------------------------------------------------------------------
// WKV: direct r/k/v/g bf16 reads (g pre-silu'd), readout, groupnorm, gate.
// ---------------------------------------------------------------------------
__global__ __launch_bounds__(256) void k_wkv(
    const u16* __restrict__ rb, const u16* __restrict__ kb,
    const u16* __restrict__ vb, const u16* __restrict__ gb,
    const float* __restrict__ state, const int* __restrict__ ip,
    const float* __restrict__ fa, const float* __restrict__ gw,
    const float* __restrict__ gbias, u16* __restrict__ t_o) {
  int t = threadIdx.x, w = t >> 6, lane = t & 63;
  int flat = blockIdx.x * 4 + w;
  int b = flat >> 5, h = flat & 31;
  size_t base = ((size_t)b << 11) + (h << 6) + lane;
  float r  = bf2f(rb[base]);
  float kv = bf2f(kb[base]);
  float vv = bf2f(vb[base]);
  float gg = bf2f(gb[base]);
  float f  = fa[(h << 6) + lane];
  __shared__ float rs[4][64];
  rs[w][lane] = r;
  __syncthreads();
  float c = r * f * kv;
#pragma unroll
  for (int off = 32; off; off >>= 1) c += __shfl_xor(c, off);

  const float* sp = state + ((size_t)b * 66 + (size_t)66 * ip[0] + 2 + 2 * h) * 2048;
  int q = lane >> 4, jj = lane & 15;
  float yp0 = 0.f, yp1 = 0.f, yp2 = 0.f, yp3 = 0.f;
#pragma unroll
  for (int ib = 0; ib < 16; ++ib) {
    int i = ib * 4 + q;
    float4 sv = *(const float4*)(sp + ((i >> 5) * 2048) + ((i & 31) << 6) + jj * 4);
    float ri = rs[w][i];
    yp0 += ri * sv.x; yp1 += ri * sv.y; yp2 += ri * sv.z; yp3 += ri * sv.w;
  }
#pragma unroll
  for (int off = 16; off <= 32; off <<= 1) {
    yp0 += __shfl_xor(yp0, off); yp1 += __shfl_xor(yp1, off);
    yp2 += __shfl_xor(yp2, off); yp3 += __shfl_xor(yp3, off);
  }
  int src = lane >> 2, cc = lane & 3;
  float t0 = __shfl(yp0, src), t1 = __shfl(yp1, src);
  float t2 = __shfl(yp2, src), t3 = __shfl(yp3, src);
  float y = cc == 0 ? t0 : cc == 1 ? t1 : cc == 2 ? t2 : t3;
  y += c * vv;
  float s1 = y, s2 = y * y;
#pragma unroll
  for (int off = 32; off; off >>= 1) { s1 += __shfl_xor(s1, off); s2 += __shfl_xor(s2, off); }
  float mu = s1 * (1.f / 64.f);
  float var = s2 * (1.f / 64.f) - mu * mu;
  float yn = (y - mu) * rsqrtf(var + 1e-5f);
  float tg = (yn * gw[(h << 6) + lane] + gbias[(h << 6) + lane]) * gg;
  t_o[base] = f2bf(tg);
}

// ---------------------------------------------------------------------------
extern "C" void kernel_launch(void* const* d_in, const int* in_sizes, int n_in,
                              void* d_out, int out_size, void* d_ws, size_t ws_size,
                              hipStream_t stream) {
  const float* x      = (const float*)d_in[0];
  const float* state  = (const float*)d_in[1];
  const float* ln1_w  = (const float*)d_in[2];
  const float* ln1_b  = (const float*)d_in[3];
  const float* ln2_w  = (const float*)d_in[4];
  const float* ln2_b  = (const float*)d_in[5];
  const float* maa_x  = (const float*)d_in[6];
  const float* maa_k  = (const float*)d_in[8];
  const float* maa_v  = (const float*)d_in[9];
  const float* maa_r  = (const float*)d_in[10];
  const float* maa_g  = (const float*)d_in[11];
  const float* maa_w1 = (const float*)d_in[12];
  const float* maa_w2 = (const float*)d_in[13];
  // decay (14,15,16) dead: w gate never reaches the returned output
  const float* faaaa  = (const float*)d_in[17];
  const float* Wr     = (const float*)d_in[18];
  const float* Wk     = (const float*)d_in[19];
  const float* Wv     = (const float*)d_in[20];
  const float* Wo     = (const float*)d_in[21];
  const float* Wg     = (const float*)d_in[22];
  const float* gn_w   = (const float*)d_in[23];
  const float* gn_b   = (const float*)d_in[24];
  const float* fmk    = (const float*)d_in[25];
  const float* fmr    = (const float*)d_in[26];
  const float* fWk    = (const float*)d_in[27];
  const float* fWr    = (const float*)d_in[28];
  const float* fWv    = (const float*)d_in[29];
  const int*   ip     = (const int*)d_in[30];
  float* out = (float*)d_out;

  char* wsb = (char*)d_ws;
  const size_t MB = 1ull << 20;
  u16* wbf   = (u16*)(wsb + 0 * MB);     // 8 x [2048,2048] bf16 = 64 MB
  u16* w1t   = (u16*)(wsb + 64 * MB);
  u16* w2t   = (u16*)(wsb + 66 * MB);
  u16* xn    = (u16*)(wsb + 68 * MB);
  u16* sx    = (u16*)(wsb + 72 * MB);
  u16* a1    = (u16*)(wsb + 76 * MB);
  float* p2  = (float*)(wsb + 80 * MB);  // [4][1024,320] f32
  u16* xxx   = (u16*)(wsb + 86 * MB);
  u16* xk    = (u16*)(wsb + 87 * MB);
  u16* xv    = (u16*)(wsb + 91 * MB);
  u16* xr    = (u16*)(wsb + 95 * MB);
  u16* xg    = (u16*)(wsb + 99 * MB);
  u16* rb    = (u16*)(wsb + 103 * MB);   // [1024,2048] bf16 each
  u16* kb    = (u16*)(wsb + 107 * MB);
  u16* vb    = (u16*)(wsb + 111 * MB);
  u16* gb    = (u16*)(wsb + 115 * MB);
  u16* tb    = (u16*)(wsb + 119 * MB);
  u16* p6    = (u16*)(wsb + 123 * MB);   // [4][1024,2048] bf16
  u16* x1b   = (u16*)(wsb + 139 * MB);   // [1024,2048] bf16
  u16* xk2   = (u16*)(wsb + 143 * MB);
  u16* xr2   = (u16*)(wsb + 147 * MB);
  u16* p8    = (u16*)(wsb + 151 * MB);   // [4][1024,2048] bf16
  u16* rr    = (u16*)(wsb + 167 * MB);
  u16* kkb   = (u16*)(wsb + 171 * MB);
  u16* p9    = (u16*)(wsb + 175 * MB);   // [4][1024,2048] bf16; end 191 MB

  const size_t WSQ = 4194304, S = 2097152;
  u16* bWr = wbf + 0 * WSQ; u16* bWk = wbf + 1 * WSQ; u16* bWv = wbf + 2 * WSQ;
  u16* bWg = wbf + 3 * WSQ; u16* bWo = wbf + 4 * WSQ; u16* bfWr = wbf + 5 * WSQ;
  u16* bfWk = wbf + 6 * WSQ; u16* bfWv = wbf + 7 * WSQ;

  auto mkd = [](const u16* A, const u16* B, void* C, const void* p1,
                const void* p2_, const float* pvec, int lda, int ldb, int ldc,
                int N, int K, int k0, int epf) {
    GemmDesc d; d.A = A; d.B = B; d.C = C; d.p1 = p1; d.p2 = p2_; d.pvec = pvec;
    d.lda = lda; d.ldb = ldb; d.ldc = ldc; d.N = N; d.K = K; d.k0 = k0; d.ep = epf;
    return d;
  };

  CvtArgs ca; ca.s[0] = Wr; ca.s[1] = Wk; ca.s[2] = Wv; ca.s[3] = Wg;
  ca.s[4] = Wo; ca.s[5] = fWr; ca.s[6] = fWk; ca.s[7] = fWv;

  static const int LDS2 = 147456;        // k_gemm2: 3 x 48 KB ring
  hipFuncSetAttribute((const void*)k_gemm2,
                      hipFuncAttributeMaxDynamicSharedMemorySize, LDS2);

  // 1) LoRA weight transpose-cvt + LN1 token-shift
  k_cvt_ln<<<5632, 256, 0, stream>>>(maa_w1, maa_w2, w1t, w2t,
                                     x, state, ip, ln1_w, ln1_b, maa_x, xn, sx, a1);

  // 2) p2[j] = a1 @ w1t^T (K-slice j)  + big-8 cvt first half (Wr,Wk,Wv,Wg)
  {
    GemmBatch g{}; g.bpg = 8 * 3;
    for (int j = 0; j < 4; ++j)
      g.g[j] = mkd(a1, w1t, p2 + (size_t)j * 327680, nullptr, nullptr, nullptr,
                   2048, 2048, 320, 320, 512, j * 512, EP_STOREF);
    k_gemmc<<<96 + 8192, 256, 0, stream>>>(g, 96, ca, wbf, 0);
  }
  k_tanhpack<<<1280, 256, 0, stream>>>(p2, xxx);

  // 3) LoRA mix j=1..4  + big-8 cvt second half (Wo,fWr,fWk,fWv)
  {
    GemmBatch g{}; g.bpg = 8 * 16;
    const float* mv[4] = {maa_k, maa_v, maa_r, maa_g};
    u16* tv[4] = {xk, xv, xr, xg};
    for (int j = 1; j <= 4; ++j)
      g.g[j - 1] = mkd(xxx + j * 64, w2t + (size_t)(j - 1) * 131072, tv[j - 1],
                       xn, sx, mv[j - 1], 320, 64, 2048, 2048, 64, 0, EP_MIX);
    k_gemmc<<<512 + 8192, 256, 0, stream>>>(g, 512, ca, wbf, 8192);
  }

  // 4) r,k,v,g GEMMs -> direct bf16 outputs (k_gemm2, no split-K, 4x64=256 blocks)
  {
    GemmBatch g{}; g.bpg = 8 * 8;
    g.g[0] = mkd(xr, bWr, rb, nullptr, nullptr, nullptr, 2048, 2048, 2048, 2048, 2048, 0, EP_STORE);
    g.g[1] = mkd(xk, bWk, kb, nullptr, nullptr, nullptr, 2048, 2048, 2048, 2048, 2048, 0, EP_STORE);
    g.g[2] = mkd(xv, bWv, vb, nullptr, nullptr, nullptr, 2048, 2048, 2048, 2048, 2048, 0, EP_STORE);
    g.g[3] = mkd(xg, bWg, gb, nullptr, nullptr, nullptr, 2048, 2048, 2048, 2048, 2048, 0, EP_SILU);
    k_gemm2<<<256, 512, LDS2, stream>>>(g);
  }

  // 5) WKV + groupnorm + gate (direct reads)
  k_wkv<<<8192, 256, 0, stream>>>(rb, kb, vb, gb, state, ip, faaaa, gn_w, gn_b, tb);

  // 6) p6[s] = tb @ Wo^T (k_gemm2, split-K 4, 256 blocks, bf16 partials)
  {
    GemmBatch g{}; g.bpg = 8 * 8;
    for (int s = 0; s < 4; ++s)
      g.g[s] = mkd(tb, bWo, p6 + (size_t)s * S, nullptr, nullptr, nullptr,
                   2048, 2048, 2048, 2048, 512, s * 512, EP_STORE);
    k_gemm2<<<256, 512, LDS2, stream>>>(g);
  }

  // 7) x1 = x + sum(p6); LN2 + ffn shift (x1 stored bf16)
  k_ln_mix2<<<1024, 256, 0, stream>>>(x, p6, state, ip, ln2_w, ln2_b, fmk, fmr,
                                      xk2, xr2, x1b);

  // 8) p8[0..1] = xr2@fWr^T; p8[2..3] = xk2@fWk^T (k_gemm2, split-K 2, 256 blocks)
  {
    GemmBatch g{}; g.bpg = 8 * 8;
    for (int s = 0; s < 2; ++s) {
      g.g[s]     = mkd(xr2, bfWr, p8 + (size_t)s * S, nullptr, nullptr, nullptr,
                       2048, 2048, 2048, 2048, 1024, s * 1024, EP_STORE);
      g.g[2 + s] = mkd(xk2, bfWk, p8 + (size_t)(2 + s) * S, nullptr, nullptr, nullptr,
                       2048, 2048, 2048, 2048, 1024, s * 1024, EP_STORE);
    }
    k_gemm2<<<256, 512, LDS2, stream>>>(g);
  }
  k_act<<<2048, 256, 0, stream>>>(p8, rr, kkb);

  // 9) p9[s] = kk @ fWv^T (k_gemm2, split-K 4, 256 blocks, bf16 partials)
  {
    GemmBatch g{}; g.bpg = 8 * 8;
    for (int s = 0; s < 4; ++s)
      g.g[s] = mkd(kkb, bfWv, p9 + (size_t)s * S, nullptr, nullptr, nullptr,
                   2048, 2048, 2048, 2048, 512, s * 512, EP_STORE);
    k_gemm2<<<256, 512, LDS2, stream>>>(g);
  }

  // 10) out = x1b + rr * sum(p9)
  k_fin<<<1024, 256, 0, stream>>>(x1b, p9, rr, out);
}